// Round 1
// 159.649 us; speedup vs baseline: 1.1110x; 1.1110x over previous
//
#include <hip/hip_runtime.h>

// Causal MHA, B=128 T=256 C=384 H=6 d=64, fp32 in/out.
// prep: X->bf16, W->W^T bf16 (Wq pre-scaled by 1/sqrt(C)*log2e).
// fused: one block per (b,h), 512 thr = 8 waves.
//   Phase A: QKV projection [256 tok x 192 n'] from Xbf via global_load_lds(16B),
//            XOR-swizzled staging tiles (verified pattern), acc 24x f32x4/thread.
//   Epilogue: acc -> LDS Q-rows / K-rows / V^T, XOR bank-swizzled.
//   Phase B: flash attention fully from LDS; waves take balanced group pairs
//            {w, 15-w} (5 causal 64-key tile visits per wave, kf/vf shared).

typedef unsigned short u16;
typedef float f32x4 __attribute__((ext_vector_type(4)));
typedef short s16x8 __attribute__((ext_vector_type(8)));

static constexpr int BB = 128;
static constexpr int TT = 256;
static constexpr int CC = 384;
static constexpr int HH = 6;
static constexpr int DD = 64;
static constexpr int MM = BB * TT;  // 32768

// ws layout (u16): WT3 [1152][384] | Xbf [M][384]
static constexpr size_t WTOFF = 0;
static constexpr size_t XOFF  = (size_t)3 * CC * CC;

// (1/sqrt(384)) * log2(e): folded into Wq so attn logits are base-2
static constexpr float CSC = 0.07362242194579907f;

__device__ __forceinline__ u16 f2bf(float f) {
  unsigned u = __float_as_uint(f);
  u += 0x7fffu + ((u >> 16) & 1u);   // RTN-even
  return (u16)(u >> 16);
}

// async global->LDS, 16 B/lane; LDS dest = wave-uniform base + lane*16 (m104)
__device__ __forceinline__ void g2l16(const u16* g, u16* l) {
  __builtin_amdgcn_global_load_lds(
      (const __attribute__((address_space(1))) u16*)g,
      (__attribute__((address_space(3))) u16*)l, 16, 0, 0);
}

// ---------- prep: X fp32->bf16 (blocks 0..6143) + W^T (blocks 6144..7871) ----------
__global__ void prep(const float* __restrict__ X, const float* __restrict__ Wq,
                     const float* __restrict__ Wk, const float* __restrict__ Wv,
                     u16* __restrict__ ws) {
  int bx = blockIdx.x;
  if (bx < 6144) {
    size_t i = (size_t)(bx * 256 + threadIdx.x) * 8;
    f32x4 a0 = *(const f32x4*)(X + i);
    f32x4 a1 = *(const f32x4*)(X + i + 4);
    s16x8 ab;
#pragma unroll
    for (int j = 0; j < 4; ++j) { ab[j] = (short)f2bf(a0[j]); ab[4 + j] = (short)f2bf(a1[j]); }
    *(s16x8*)(ws + XOFF + i) = ab;
  } else {
    int j = bx - 6144;
    int z = j / 576;
    const float* W = (z == 0) ? Wq : (z == 1) ? Wk : Wv;
    const float sc = (z == 0) ? CSC : 1.0f;
    u16* WT = ws + WTOFF + (size_t)z * CC * CC;
    int i = (j % 576) * 256 + threadIdx.x;
    int k = i / CC, n = i % CC;
    WT[(size_t)n * CC + k] = f2bf(W[i] * sc);
  }
}

// ---------- fused QKV projection + flash attention ----------
__global__ __launch_bounds__(512, 2) void fused(const u16* __restrict__ ws,
                                                float* __restrict__ out) {
  // XCD clustering: 6 heads of same b share ids congruent mod 8 -> same XCD L2
  const int bid = blockIdx.x;
  const int xc = bid & 7;
  const int g5 = bid >> 3;           // 0..95
  const int b = xc * 16 + g5 / 6;
  const int h = g5 % 6;

  __shared__ u16 Xs[256][64];        // phase A: X chunk; phase B: Q rows (swizzled)
  __shared__ u16 Ws[192][64];        // phase A: W chunk; phase B: Ps [8][16][72]
  __shared__ u16 Ks[256][64];        // K rows, XOR-swizzled by (tok&7)<<3
  __shared__ u16 VTs[64][256];       // V^T, XOR-swizzled by (d&15)<<3

  const int tid = threadIdx.x;
  const int lane = tid & 63;
  const int w = tid >> 6;            // 0..7
  const int quad = lane >> 4;
  const int col = lane & 15;

  const u16* Xg = ws + XOFF + (size_t)b * TT * CC;   // [256][384]
  const u16* Wg = ws + WTOFF;                        // [1152][384]

  const int rl = lane >> 3;          // row within 8-row staging chunk
  const int gb = (lane & 7) ^ rl;    // swizzled 8-elem block for this lane

  const int wm = (w >> 1) * 64;      // token quadrant base
  const int wn = (w & 1) * 96;       // n' half base (Q:0-63 K:64-127 V:128-191)

  // ---------------- Phase A: 256x192 projection, BK=64, 6 chunks ----------------
  f32x4 acc[4][6] = {};

  for (int kt = 0; kt < 6; ++kt) {
    if (kt) __syncthreads();         // WAR: all waves done reading prev chunk
#pragma unroll
    for (int i = 0; i < 4; ++i) {
      int r0 = w * 32 + i * 8;
      g2l16(Xg + (size_t)(r0 + rl) * CC + kt * 64 + gb * 8, &Xs[r0][0]);
    }
#pragma unroll
    for (int i = 0; i < 3; ++i) {
      int r0 = w * 24 + i * 8;
      int rr = r0 + rl;
      int z = rr >> 6, nn = rr & 63;
      g2l16(Wg + (size_t)(z * CC + h * DD + nn) * CC + kt * 64 + gb * 8, &Ws[r0][0]);
    }
    __syncthreads();                 // drains vmcnt(0) then barrier (RAW)

    s16x8 af[4][2];
#pragma unroll
    for (int mt = 0; mt < 4; ++mt)
#pragma unroll
      for (int ks = 0; ks < 2; ++ks)
        af[mt][ks] = *(const s16x8*)(&Xs[wm + mt * 16 + col]
                                        [(((ks * 4 + quad) ^ (col & 7)) * 8)]);
#pragma unroll
    for (int nt = 0; nt < 6; ++nt) {
      s16x8 bf[2];
#pragma unroll
      for (int ks = 0; ks < 2; ++ks)
        bf[ks] = *(const s16x8*)(&Ws[wn + nt * 16 + col]
                                    [(((ks * 4 + quad) ^ (col & 7)) * 8)]);
#pragma unroll
      for (int ks = 0; ks < 2; ++ks)
#pragma unroll
        for (int mt = 0; mt < 4; ++mt)
          acc[mt][nt] = __builtin_amdgcn_mfma_f32_16x16x32_bf16(
              af[mt][ks], bf[ks], acc[mt][nt], 0, 0, 0);
    }
  }
  __syncthreads();  // all waves done with Xs/Ws before overlay writes

  // ---------------- Epilogue: acc -> Q(=Xs)/K rows, V^T; XOR bank-swizzle ----------
  // Q/K rows [tok][64]: elem d stored at d ^ ((tok&7)<<3).
  // V^T rows [d][256]: elem tok stored at tok ^ ((d&15)<<3) (8B-unit safe: XOR bits>=3).
#pragma unroll
  for (int mt = 0; mt < 4; ++mt) {
    int tokb = wm + mt * 16 + quad * 4;
#pragma unroll
    for (int nt = 0; nt < 6; ++nt) {
      int gn = wn + nt * 16 + col;           // wave-uniform bucket per (w,nt)
      if (gn < 128) {
        u16* dst = (gn < 64) ? (u16*)Xs : (u16*)Ks;
        int d = gn & 63;
#pragma unroll
        for (int r = 0; r < 4; ++r) {
          int tok = tokb + r;
          dst[tok * 64 + (d ^ ((tok & 7) << 3))] = f2bf(acc[mt][nt][r]);
        }
      } else {
        int d = gn - 128;
        uint2 pk;
        pk.x = (unsigned)f2bf(acc[mt][nt][0]) | ((unsigned)f2bf(acc[mt][nt][1]) << 16);
        pk.y = (unsigned)f2bf(acc[mt][nt][2]) | ((unsigned)f2bf(acc[mt][nt][3]) << 16);
        *(uint2*)((u16*)VTs + d * 256 + (tokb ^ ((d & 15) << 3))) = pk;
      }
    }
  }
  __syncthreads();

  // ---------------- Phase B: flash attention from LDS, barrier-free ----------------
  // wave w owns q 16-row groups {w, 15-w}: every wave exactly 5 tile visits.
  u16* Ps = (u16*)Ws + (size_t)w * 1152 + (size_t)col * 72;  // per-wave [16][72]

  s16x8 qf[2][2];
#pragma unroll
  for (int gi = 0; gi < 2; ++gi) {
    int g = gi ? (15 - w) : w;
    int q = g * 16 + col;
#pragma unroll
    for (int ks = 0; ks < 2; ++ks)
      qf[gi][ks] = *(const s16x8*)((u16*)Xs + q * 64 +
                                   (((ks * 4 + quad) ^ (q & 7)) << 3));
  }

  f32x4 o[2][4] = {};
  float mst[2] = {-1.0e30f, -1.0e30f}, lst[2] = {0.0f, 0.0f};

  const int kthi = (15 - w) >> 2;    // hi group's diagonal tile
  for (int kt = 0; kt <= kthi; ++kt) {
    s16x8 kf[4][2], vf[4][2];
#pragma unroll
    for (int nt = 0; nt < 4; ++nt)
#pragma unroll
      for (int ks = 0; ks < 2; ++ks) {
        int key = kt * 64 + nt * 16 + col;
        kf[nt][ks] = *(const s16x8*)((u16*)Ks + key * 64 +
                                     (((ks * 4 + quad) ^ (key & 7)) << 3));
        int d = nt * 16 + col;
        vf[nt][ks] = *(const s16x8*)((u16*)VTs + d * 256 +
                                     ((kt * 64 + ks * 32 + quad * 8) ^ ((d & 15) << 3)));
      }

#pragma unroll
    for (int gi = 0; gi < 2; ++gi) {
      const int g = gi ? (15 - w) : w;
      const int gmax = g >> 2;
      if (kt > gmax) continue;       // wave-uniform

      // S^T tiles: row = key = nt*16+quad*4+r, col = q
      f32x4 s[4] = {};
#pragma unroll
      for (int ks = 0; ks < 2; ++ks)
#pragma unroll
        for (int nt = 0; nt < 4; ++nt)
          s[nt] = __builtin_amdgcn_mfma_f32_16x16x32_bf16(kf[nt][ks], qf[gi][ks],
                                                          s[nt], 0, 0, 0);

      const int qq = (g & 3) * 16 + col;   // q offset within diagonal 64-tile
      const bool diag = (kt == gmax);
      float rmax = -1.0e30f;
#pragma unroll
      for (int nt = 0; nt < 4; ++nt)
#pragma unroll
        for (int r = 0; r < 4; ++r) {
          float t = s[nt][r];
          if (diag && (nt * 16 + quad * 4 + r) > qq) t = -1.0e30f;
          s[nt][r] = t;
          rmax = fmaxf(rmax, t);
        }
      rmax = fmaxf(rmax, __shfl_xor(rmax, 16));
      rmax = fmaxf(rmax, __shfl_xor(rmax, 32));

      float mn = fmaxf(mst[gi], rmax);
      float alpha = exp2f(mst[gi] - mn);
      mst[gi] = mn;

      float lsum = 0.0f;
      unsigned pk[4][2];
#pragma unroll
      for (int nt = 0; nt < 4; ++nt) {
        float p0 = exp2f(s[nt][0] - mn), p1 = exp2f(s[nt][1] - mn);
        float p2 = exp2f(s[nt][2] - mn), p3 = exp2f(s[nt][3] - mn);
        lsum += (p0 + p1) + (p2 + p3);
        pk[nt][0] = (unsigned)f2bf(p0) | ((unsigned)f2bf(p1) << 16);
        pk[nt][1] = (unsigned)f2bf(p2) | ((unsigned)f2bf(p3) << 16);
      }
      lst[gi] = lst[gi] * alpha + lsum;

#pragma unroll
      for (int dt = 0; dt < 4; ++dt)
#pragma unroll
        for (int r = 0; r < 4; ++r) o[gi][dt][r] *= alpha;

      // P^T -> LDS [q][key] round-trip (per-wave private buffer)
      asm volatile("s_waitcnt lgkmcnt(0)" ::: "memory");  // WAR vs prev reads
#pragma unroll
      for (int nt = 0; nt < 4; ++nt)
        *(uint2*)(Ps + nt * 16 + quad * 4) = make_uint2(pk[nt][0], pk[nt][1]);
      asm volatile("s_waitcnt lgkmcnt(0)" ::: "memory");  // own-wave visibility

      s16x8 pf[2];
#pragma unroll
      for (int ks = 0; ks < 2; ++ks)
        pf[ks] = *(const s16x8*)(Ps + ks * 32 + quad * 8);

#pragma unroll
      for (int ks = 0; ks < 2; ++ks)
#pragma unroll
        for (int dt = 0; dt < 4; ++dt)
          o[gi][dt] = __builtin_amdgcn_mfma_f32_16x16x32_bf16(vf[dt][ks], pf[ks],
                                                              o[gi][dt], 0, 0, 0);
    }
  }

  // epilogue: O^T row = d = dt*16+quad*4+r, col = q -> out[b,q,h*64+d]
#pragma unroll
  for (int gi = 0; gi < 2; ++gi) {
    int g = gi ? (15 - w) : w;
    float l = lst[gi];
    l += __shfl_xor(l, 16);
    l += __shfl_xor(l, 32);
    float inv = 1.0f / l;
    int q = g * 16 + col;
#pragma unroll
    for (int dt = 0; dt < 4; ++dt) {
      f32x4 res;
#pragma unroll
      for (int r = 0; r < 4; ++r) res[r] = o[gi][dt][r] * inv;
      *(f32x4*)(out + (size_t)(b * TT + q) * CC + h * DD + dt * 16 + quad * 4) = res;
    }
  }
}

extern "C" void kernel_launch(void* const* d_in, const int* in_sizes, int n_in,
                              void* d_out, int out_size, void* d_ws, size_t ws_size,
                              hipStream_t stream) {
  const float* x  = (const float*)d_in[0];
  const float* wq = (const float*)d_in[1];
  const float* wk = (const float*)d_in[2];
  const float* wv = (const float*)d_in[3];
  u16* ws  = (u16*)d_ws;
  float* out = (float*)d_out;

  prep<<<dim3(6144 + 1728), 256, 0, stream>>>(x, wq, wk, wv, ws);
  fused<<<dim3(BB * HH), 512, 0, stream>>>(ws, out);
}